// Round 3
// baseline (970.541 us; speedup 1.0000x reference)
//
#include <hip/hip_runtime.h>

#define NCC 1024
#define MODIN 198
#define MODOUT 68
#define HMODL 128

typedef __attribute__((ext_vector_type(8))) short s8v;   // 8 bf16 = 4 VGPR
typedef __attribute__((ext_vector_type(4))) float f4v;   // MFMA acc
typedef unsigned short ushort_t;
typedef unsigned int uint_t;

// ws layout (ushort elems): sw1 @0 (32768), sw2 @32768 (16384), mw1 @49152 (16384), mw2 @65536 (16384)
#define OFF_SW1 0
#define OFF_SW2 32768
#define OFF_MW1 49152
#define OFF_MW2 65536
#define FEATS_BYTE_OFF 262144   // feats: 8192 cells x 132 f32

__device__ __forceinline__ float fast_tanh(float x) {
    // tanh(x) = 1 - 2/(e^{2x}+1); hw exp2/rcp handle +-inf correctly, no clamp
    const float e = __builtin_amdgcn_exp2f(x * 2.885390081777927f);
    const float r = __builtin_amdgcn_rcpf(e + 1.f);
    return fmaf(-2.f, r, 1.f);
}
__device__ __forceinline__ float fast_sigmoid(float x) {
    const float e = __builtin_amdgcn_exp2f(x * -1.4426950408889634f);
    return __builtin_amdgcn_rcpf(e + 1.f);
}
__device__ __forceinline__ ushort_t f2bf(float x) {   // RNE f32->bf16
    uint_t u = __builtin_bit_cast(uint_t, x);
    u += 0x7FFFu + ((u >> 16) & 1u);
    return (ushort_t)(u >> 16);
}
__device__ __forceinline__ uint_t pk2(float a, float b) {
    return (uint_t)f2bf(a) | ((uint_t)f2bf(b) << 16);
}
// XOR swizzle on LDS byte offsets (16B granule)
#define SWZ(byteoff, row) ((byteoff) ^ (((row) & 7) << 4))

// ---------------------------------------------------------------------------
// Kernel 0: convert the 4 shared MLP weight matrices to bf16 once per launch
// ---------------------------------------------------------------------------
__global__ __launch_bounds__(256)
void mg_cvtw(const float* __restrict__ sw1, const float* __restrict__ sw2,
             const float* __restrict__ mw1, const float* __restrict__ mw2,
             ushort_t* __restrict__ o) {
    const int i = blockIdx.x * 256 + threadIdx.x;   // grid 320 -> 81920 exact
    float v;
    if (i < 32768)      v = sw1[i];
    else if (i < 49152) v = sw2[i - 32768];
    else if (i < 65536) v = mw1[i - 49152];
    else                v = mw2[i - 65536];
    o[i] = f2bf(v);
}

// ---------------------------------------------------------------------------
// Kernel 1: per (b, cell) block; 512 threads = 8 waves.
// mfma_f32_16x16x32_bf16 layouts:
//   A-frag: row = lane&15, k = (lane>>4)*8 + j (contiguous)
//   B-frag (from [N][K] row-major): col = lane&15, k contiguous
//   D: col = lane&15, row = (lane>>4)*4 + reg
// Wave split (w = t>>6 in 0..7):
//   L1 (P3/P5): wave owns hid cols [32w, 32w+32): 2 col-tiles x 4 row-tiles
//   small GEMMs (P1/P4/P6): colt = w&3 (16 d-cols), rh = w>>2 (32 rows)
// ---------------------------------------------------------------------------
__global__ __launch_bounds__(512, 6)
void mg_cell_kernel(
    const float* __restrict__ xp,   const float* __restrict__ hp,
    const float* __restrict__ msgp, const float* __restrict__ Wp,
    const float* __restrict__ decayp, const float* __restrict__ bglp,
    const float* __restrict__ nidp,
    const float* __restrict__ sb1,  const float* __restrict__ sgs1,
    const float* __restrict__ sgb1, const float* __restrict__ sb2,
    const float* __restrict__ sgs2, const float* __restrict__ sgb2,
    const float* __restrict__ mb1,  const float* __restrict__ mgs1,
    const float* __restrict__ mgb1, const float* __restrict__ mb2,
    const float* __restrict__ mgs2, const float* __restrict__ mgb2,
    const float* __restrict__ iw,   const float* __restrict__ ibias,
    const int*   __restrict__ c2g,  const ushort_t* __restrict__ wb,
    float* __restrict__ out_read, float* __restrict__ out_h,
    float* __restrict__ out_msg,  float* __restrict__ wsf)
{
    const int t  = threadIdx.x;
    const int bc = blockIdx.x;
    const int b  = bc >> 10, c = bc & 1023;
    const int gh = c >> 5, gwc = c & 31;
    const int lane = t & 63, w = t >> 6;
    const int cl = lane & 15, q = lane >> 4;
    const int g  = c2g[c];
    const size_t tile = (size_t)bc * 4096;

    __shared__ ushort_t sHid[16384];   // [64][256] bf16, 32KB; first 16KB overlays sW|sMsgT
    __shared__ ushort_t sIn[8192];     // [64][128] bf16: [received|h]; later s_out f32 [64][64]
    __shared__ float s_scr[1024];      // [0:256]=inc, [256:512]=inj; after P2: [0:512]=hpart, [512:1024]=mpart
    __shared__ float s_x[64];
    __shared__ float s_dec[64];
    __shared__ float s_wsum[8];
    __shared__ float s_dsum;

    ushort_t* sW    = sHid;            // [64][64], row stride 128B
    ushort_t* sMsgT = sHid + 4096;     // [64 d][64 m]
    float*    s_out = (float*)sIn;     // [64][64] f32 (P6 epilogue scratch)

    // ================= P0: staging =================
    {   // W -> sW bf16 (+ sum|W|): thread: n = t>>3, 8 cols
        const int n = t >> 3, m0 = (t & 7) * 8;
        const float* src = Wp + tile + n * 64 + m0;
        const float4 v0 = *(const float4*)(src);
        const float4 v1 = *(const float4*)(src + 4);
        float wsum = fabsf(v0.x) + fabsf(v0.y) + fabsf(v0.z) + fabsf(v0.w)
                   + fabsf(v1.x) + fabsf(v1.y) + fabsf(v1.z) + fabsf(v1.w);
        *(uint_t*)((char*)sW + SWZ(n * 128 + (m0 + 0) * 2, n)) = pk2(v0.x, v0.y);
        *(uint_t*)((char*)sW + SWZ(n * 128 + (m0 + 2) * 2, n)) = pk2(v0.z, v0.w);
        *(uint_t*)((char*)sW + SWZ(n * 128 + (m0 + 4) * 2, n)) = pk2(v1.x, v1.y);
        *(uint_t*)((char*)sW + SWZ(n * 128 + (m0 + 6) * 2, n)) = pk2(v1.z, v1.w);
        #pragma unroll
        for (int off = 32; off > 0; off >>= 1) wsum += __shfl_down(wsum, off);
        if (lane == 0) s_wsum[w] = wsum;
    }
    #pragma unroll
    for (int i = 0; i < 2; i++) {   // msg^T -> sMsgT bf16
        const int m = (t >> 4) + i * 32, d0 = (t & 15) * 4;
        const float4 v = *(const float4*)(msgp + tile + (size_t)m * 64 + d0);
        *(ushort_t*)((char*)sMsgT + SWZ((d0 + 0) * 128 + m * 2, d0 + 0)) = f2bf(v.x);
        *(ushort_t*)((char*)sMsgT + SWZ((d0 + 1) * 128 + m * 2, d0 + 1)) = f2bf(v.y);
        *(ushort_t*)((char*)sMsgT + SWZ((d0 + 2) * 128 + m * 2, d0 + 2)) = f2bf(v.z);
        *(ushort_t*)((char*)sMsgT + SWZ((d0 + 3) * 128 + m * 2, d0 + 3)) = f2bf(v.w);
    }
    #pragma unroll
    for (int i = 0; i < 2; i++) {   // h -> sIn[:,64:128] bf16
        const int n = (t >> 4) + i * 32, d0 = (t & 15) * 4;
        const float4 v = *(const float4*)(hp + tile + (size_t)n * 64 + d0);
        *(uint_t*)((char*)sIn + SWZ(n * 256 + (64 + d0) * 2, n))     = pk2(v.x, v.y);
        *(uint_t*)((char*)sIn + SWZ(n * 256 + (64 + d0 + 2) * 2, n)) = pk2(v.z, v.w);
    }
    if (t < 16)
        *(float4*)&s_x[t * 4] = *(const float4*)&xp[((size_t)b * NCC + c) * 64 + t * 4];
    if (t < 256) {   // gated border incoming: wave p = w (0..3)
        const int p = w, d = lane;
        int ok, nc2, qq;
        if      (p == 0) { ok = (gh > 0);   nc2 = c - 32; qq = 1; }
        else if (p == 1) { ok = (gh < 31);  nc2 = c + 32; qq = 0; }
        else if (p == 2) { ok = (gwc > 0);  nc2 = c - 1;  qq = 3; }
        else             { ok = (gwc < 31); nc2 = c + 1;  qq = 2; }
        float v = 0.f;
        if (ok) v = msgp[((size_t)b * NCC + nc2) * 4096 + (8 + qq) * 64 + d];
        s_scr[p * 64 + d] = fast_sigmoid(bglp[(size_t)bc * 4 + p]) * v;
    }
    if (w == 0) {
        const float dl = decayp[(size_t)bc * 64 + lane];
        s_dec[lane] = fast_sigmoid(dl);
        float v = dl;
        #pragma unroll
        for (int off = 32; off > 0; off >>= 1) v += __shfl_down(v, off);
        if (lane == 0) s_dsum = v;
    }
    __syncthreads();

    // ================= P1: inject (VALU) + W@msg (MFMA) =================
    {
        const int o = t >> 1, hf = t & 1;
        const float* wrow = iw + (size_t)g * 16384 + o * 64 + hf * 32;
        float acc = 0.f;
        #pragma unroll
        for (int i = 0; i < 32; i += 4) {
            const float4 w4 = *(const float4*)(wrow + i);
            acc = fmaf(w4.x, s_x[hf * 32 + i + 0], acc);
            acc = fmaf(w4.y, s_x[hf * 32 + i + 1], acc);
            acc = fmaf(w4.z, s_x[hf * 32 + i + 2], acc);
            acc = fmaf(w4.w, s_x[hf * 32 + i + 3], acc);
        }
        acc += __shfl_xor(acc, 1);
        if (hf == 0) s_scr[256 + o] = acc + ibias[g * 256 + o];
    }
    const f4v fzero = {0.f, 0.f, 0.f, 0.f};
    const int dcol = 16 * (w & 3) + cl;    // d-column for P1/P2/P4/P6
    const int rh   = w >> 2;               // row-half for P1/P2/P4/P6
    f4v wm[2] = {fzero, fzero};
    {
        #pragma unroll
        for (int ks = 0; ks < 2; ks++) {
            const int k0 = ks * 32 + q * 8;
            const s8v bf = *(const s8v*)((const char*)sMsgT + SWZ(dcol * 128 + k0 * 2, dcol));
            #pragma unroll
            for (int rt2 = 0; rt2 < 2; rt2++) {
                const int ar = (rh * 2 + rt2) * 16 + cl;
                const s8v af = *(const s8v*)((const char*)sW + SWZ(ar * 128 + k0 * 2, ar));
                wm[rt2] = __builtin_amdgcn_mfma_f32_16x16x32_bf16(af, bf, wm[rt2], 0, 0, 0);
            }
        }
    }
    __syncthreads();

    // ================= P2: received(+inject+border) -> sIn[:,0:64] =================
    {
        #pragma unroll
        for (int rt2 = 0; rt2 < 2; rt2++)
            #pragma unroll
            for (int r = 0; r < 4; r++) {
                const int n = (rh * 2 + rt2) * 16 + q * 4 + r;
                float v = wm[rt2][r];
                if (n < 4)                 v += s_scr[256 + n * 64 + dcol];
                else if (n >= 8 && n < 12) v += s_scr[(n - 8) * 64 + dcol];
                *(ushort_t*)((char*)sIn + SWZ(n * 256 + dcol * 2, n)) = f2bf(v);
            }
    }
    __syncthreads();

    // ================= P3: state L1 [64x128]@[128x256]^T -> sHid =================
    {
        f4v acc[4][2];
        #pragma unroll
        for (int i = 0; i < 4; i++) { acc[i][0] = fzero; acc[i][1] = fzero; }
        const ushort_t* wb1 = wb + OFF_SW1;
        #pragma unroll
        for (int ks = 0; ks < 4; ks++) {
            const int k0 = ks * 32 + q * 8;
            s8v bfr[2], afr[4];
            #pragma unroll
            for (int ct = 0; ct < 2; ct++)
                bfr[ct] = *(const s8v*)(wb1 + (32 * w + ct * 16 + cl) * 128 + k0);
            #pragma unroll
            for (int rt = 0; rt < 4; rt++) {
                const int ar = rt * 16 + cl;
                afr[rt] = *(const s8v*)((const char*)sIn + SWZ(ar * 256 + k0 * 2, ar));
            }
            #pragma unroll
            for (int rt = 0; rt < 4; rt++)
                #pragma unroll
                for (int ct = 0; ct < 2; ct++)
                    acc[rt][ct] = __builtin_amdgcn_mfma_f32_16x16x32_bf16(afr[rt], bfr[ct], acc[rt][ct], 0, 0, 0);
        }
        #pragma unroll
        for (int ct = 0; ct < 2; ct++) {
            const int hcol = 32 * w + ct * 16 + cl;
            const float b1 = sb1[hcol], g1 = sgs1[g * 256 + hcol], o1 = sgb1[g * 256 + hcol];
            #pragma unroll
            for (int rt = 0; rt < 4; rt++)
                #pragma unroll
                for (int r = 0; r < 4; r++) {
                    const int n = rt * 16 + q * 4 + r;
                    const float vv = fast_tanh(fmaf(acc[rt][ct][r] + b1, g1, o1));
                    *(ushort_t*)((char*)sHid + SWZ(n * 512 + hcol * 2, n)) = f2bf(vv);
                }
        }
    }
    __syncthreads();

    // ================= P4: state L2 -> cand -> h_new (bf16 into sIn[:,0:64]) =================
    {
        f4v a2[2] = {fzero, fzero};
        const ushort_t* wb2 = wb + OFF_SW2;
        #pragma unroll
        for (int ks = 0; ks < 8; ks++) {
            const int k0 = ks * 32 + q * 8;
            const s8v bf = *(const s8v*)(wb2 + dcol * 256 + k0);
            #pragma unroll
            for (int rt2 = 0; rt2 < 2; rt2++) {
                const int ar = (rh * 2 + rt2) * 16 + cl;
                const s8v af = *(const s8v*)((const char*)sHid + SWZ(ar * 512 + k0 * 2, ar));
                a2[rt2] = __builtin_amdgcn_mfma_f32_16x16x32_bf16(af, bf, a2[rt2], 0, 0, 0);
            }
        }
        const float b2 = sb2[dcol], g2 = sgs2[g * 64 + dcol], o2 = sgb2[g * 64 + dcol];
        #pragma unroll
        for (int rt2 = 0; rt2 < 2; rt2++)
            #pragma unroll
            for (int r = 0; r < 4; r++) {
                const int n = (rh * 2 + rt2) * 16 + q * 4 + r;
                const float cand = fast_tanh(fmaf(a2[rt2][r] + b2, g2, o2));
                const ushort_t hu = *(const ushort_t*)((const char*)sIn + SWZ(n * 256 + (64 + dcol) * 2, n));
                const float hv = __builtin_bit_cast(float, (uint_t)hu << 16);
                const float hn = fmaf(s_dec[n], hv - cand, cand);   // dec*h + (1-dec)*cand
                *(ushort_t*)((char*)sIn + SWZ(n * 256 + dcol * 2, n)) = f2bf(hn);
            }
    }
    __syncthreads();

    // ===== writeout-h: coalesced float4 stores from sIn bf16 + h_mean partials =====
    {
        float4 hm = {0.f, 0.f, 0.f, 0.f};
        #pragma unroll
        for (int i = 0; i < 2; i++) {
            const int n = i * 32 + (t >> 4), d0 = (t & 15) * 4;
            const uint2 u = *(const uint2*)((const char*)sIn + SWZ(n * 256 + d0 * 2, n));
            float4 v;
            v.x = __builtin_bit_cast(float, (uint_t)(u.x << 16));
            v.y = __builtin_bit_cast(float, (uint_t)(u.x & 0xFFFF0000u));
            v.z = __builtin_bit_cast(float, (uint_t)(u.y << 16));
            v.w = __builtin_bit_cast(float, (uint_t)(u.y & 0xFFFF0000u));
            *(float4*)(out_h + tile + (size_t)n * 64 + d0) = v;
            hm.x += v.x; hm.y += v.y; hm.z += v.z; hm.w += v.w;
        }
        #pragma unroll
        for (int m = 16; m < 64; m <<= 1) {
            hm.x += __shfl_xor(hm.x, m); hm.y += __shfl_xor(hm.y, m);
            hm.z += __shfl_xor(hm.z, m); hm.w += __shfl_xor(hm.w, m);
        }
        if (lane < 16) *(float4*)&s_scr[w * 64 + lane * 4] = hm;   // hpart[w]
    }

    // ================= P5: msg L1 [64x64]@[64x256]^T -> sHid =================
    {
        f4v acc[4][2];
        #pragma unroll
        for (int i = 0; i < 4; i++) { acc[i][0] = fzero; acc[i][1] = fzero; }
        const ushort_t* wb1 = wb + OFF_MW1;
        #pragma unroll
        for (int ks = 0; ks < 2; ks++) {
            const int k0 = ks * 32 + q * 8;
            s8v bfr[2], afr[4];
            #pragma unroll
            for (int ct = 0; ct < 2; ct++)
                bfr[ct] = *(const s8v*)(wb1 + (32 * w + ct * 16 + cl) * 64 + k0);
            #pragma unroll
            for (int rt = 0; rt < 4; rt++) {
                const int ar = rt * 16 + cl;
                afr[rt] = *(const s8v*)((const char*)sIn + SWZ(ar * 256 + k0 * 2, ar));
            }
            #pragma unroll
            for (int rt = 0; rt < 4; rt++)
                #pragma unroll
                for (int ct = 0; ct < 2; ct++)
                    acc[rt][ct] = __builtin_amdgcn_mfma_f32_16x16x32_bf16(afr[rt], bfr[ct], acc[rt][ct], 0, 0, 0);
        }
        #pragma unroll
        for (int ct = 0; ct < 2; ct++) {
            const int hcol = 32 * w + ct * 16 + cl;
            const float b1 = mb1[hcol], g1 = mgs1[g * 256 + hcol], o1 = mgb1[g * 256 + hcol];
            #pragma unroll
            for (int rt = 0; rt < 4; rt++)
                #pragma unroll
                for (int r = 0; r < 4; r++) {
                    const int n = rt * 16 + q * 4 + r;
                    const float vv = fast_tanh(fmaf(acc[rt][ct][r] + b1, g1, o1));
                    *(ushort_t*)((char*)sHid + SWZ(n * 512 + hcol * 2, n)) = f2bf(vv);
                }
        }
    }
    __syncthreads();

    // ================= P6: msg L2 -> tanh -> s_out f32 (sIn region, dead) =================
    {
        f4v a2[2] = {fzero, fzero};
        const ushort_t* wb2 = wb + OFF_MW2;
        #pragma unroll
        for (int ks = 0; ks < 8; ks++) {
            const int k0 = ks * 32 + q * 8;
            const s8v bf = *(const s8v*)(wb2 + dcol * 256 + k0);
            #pragma unroll
            for (int rt2 = 0; rt2 < 2; rt2++) {
                const int ar = (rh * 2 + rt2) * 16 + cl;
                const s8v af = *(const s8v*)((const char*)sHid + SWZ(ar * 512 + k0 * 2, ar));
                a2[rt2] = __builtin_amdgcn_mfma_f32_16x16x32_bf16(af, bf, a2[rt2], 0, 0, 0);
            }
        }
        const float b2 = mb2[dcol], g2 = mgs2[g * 64 + dcol], o2 = mgb2[g * 64 + dcol];
        #pragma unroll
        for (int rt2 = 0; rt2 < 2; rt2++)
            #pragma unroll
            for (int r = 0; r < 4; r++) {
                const int n = (rh * 2 + rt2) * 16 + q * 4 + r;
                const float mv = fast_tanh(fmaf(a2[rt2][r] + b2, g2, o2));
                *(float*)((char*)s_out + SWZ(n * 256 + dcol * 4, n)) = mv;
            }
    }
    __syncthreads();

    // ===== writeout-msg: +nid, coalesced float4 stores, msg_mean, readout =====
    {
        float4 mm = {0.f, 0.f, 0.f, 0.f};
        float4 ro = {0.f, 0.f, 0.f, 0.f};
        #pragma unroll
        for (int i = 0; i < 2; i++) {
            const int n = i * 32 + (t >> 4), d0 = (t & 15) * 4;
            float4 v = *(const float4*)((const char*)s_out + SWZ(n * 256 + d0 * 4, n));
            const float4 nv = *(const float4*)(nidp + (size_t)c * 4096 + (size_t)n * 64 + d0);
            v.x += nv.x; v.y += nv.y; v.z += nv.z; v.w += nv.w;
            *(float4*)(out_msg + tile + (size_t)n * 64 + d0) = v;
            mm.x += v.x; mm.y += v.y; mm.z += v.z; mm.w += v.w;
            if (i == 0 && w == 1) ro = v;   // rows 4..7 (n = 4+q) live in wave 1, iter 0
        }
        #pragma unroll
        for (int m = 16; m < 64; m <<= 1) {
            mm.x += __shfl_xor(mm.x, m); mm.y += __shfl_xor(mm.y, m);
            mm.z += __shfl_xor(mm.z, m); mm.w += __shfl_xor(mm.w, m);
        }
        if (lane < 16) *(float4*)&s_scr[512 + w * 64 + lane * 4] = mm;   // mpart[w]
        if (w == 1) {
            #pragma unroll
            for (int m = 16; m < 64; m <<= 1) {
                ro.x += __shfl_xor(ro.x, m); ro.y += __shfl_xor(ro.y, m);
                ro.z += __shfl_xor(ro.z, m); ro.w += __shfl_xor(ro.w, m);
            }
            if (lane < 16) {
                float4 o4 = {ro.x * 0.5f, ro.y * 0.5f, ro.z * 0.5f, ro.w * 0.5f};
                *(float4*)(out_read + ((size_t)b * NCC + c) * 64 + lane * 4) = o4;
            }
        }
    }
    __syncthreads();

    // ================= P7: feats record (130 values) =================
    if (t < 132) {
        float v = 0.f;
        if (t < 64) {
            float s = 0.f;
            #pragma unroll
            for (int ww = 0; ww < 8; ww++) s += s_scr[ww * 64 + t];
            v = s * (1.f / 64.f);
        } else if (t < 128) {
            float s = 0.f;
            #pragma unroll
            for (int ww = 0; ww < 8; ww++) s += s_scr[512 + ww * 64 + (t - 64)];
            v = s * (1.f / 64.f);
        } else if (t == 128) {
            float s = 0.f;
            #pragma unroll
            for (int ww = 0; ww < 8; ww++) s += s_wsum[ww];
            v = s * (1.f / 4096.f);
        } else if (t == 129) v = s_dsum * (1.f / 64.f);
        wsf[(size_t)bc * 132 + t] = v;
    }
}

// ---------------------------------------------------------------------------
// Kernel 2: per-cell modulation MLP (distinct weights per cell)
// ---------------------------------------------------------------------------
__global__ __launch_bounds__(256, 2)
void mg_mod_kernel(
    const float* __restrict__ wsf,   const float* __restrict__ modw1,
    const float* __restrict__ modb1, const float* __restrict__ modw2,
    const float* __restrict__ modb2, const float* __restrict__ ctxp,
    const float* __restrict__ bglp,  float* __restrict__ out_ctx,
    float* __restrict__ out_bg)
{
    const int c = blockIdx.x;
    const int t = threadIdx.x;
    __shared__ float s_f[8][MODIN];
    __shared__ float s_h2[8][HMODL];

    for (int k = t; k < 8 * MODIN; k += 256) {
        const int b = k / MODIN, f = k - b * MODIN;
        float v;
        if (f < 130)      v = wsf[((size_t)b * NCC + c) * 132 + f];
        else if (f < 194) v = ctxp[((size_t)b * NCC + c) * 64 + (f - 130)];
        else              v = bglp[((size_t)b * NCC + c) * 4 + (f - 194)];
        s_f[b][f] = v;
    }
    __syncthreads();

    {
        const int hh = t & 127, bh = (t >> 7) * 4;
        float a0 = 0.f, a1 = 0.f, a2 = 0.f, a3 = 0.f;
        const float* wp = modw1 + (size_t)c * MODIN * HMODL + hh;
        for (int f = 0; f < MODIN; f++) {
            const float wv = wp[(size_t)f * HMODL];
            a0 = fmaf(s_f[bh + 0][f], wv, a0);
            a1 = fmaf(s_f[bh + 1][f], wv, a1);
            a2 = fmaf(s_f[bh + 2][f], wv, a2);
            a3 = fmaf(s_f[bh + 3][f], wv, a3);
        }
        const float bv = modb1[(size_t)c * HMODL + hh];
        s_h2[bh + 0][hh] = fast_tanh(a0 + bv);
        s_h2[bh + 1][hh] = fast_tanh(a1 + bv);
        s_h2[bh + 2][hh] = fast_tanh(a2 + bv);
        s_h2[bh + 3][hh] = fast_tanh(a3 + bv);
    }
    __syncthreads();

    for (int idx = t; idx < 8 * MODOUT; idx += 256) {
        const int b = idx / MODOUT, o = idx - b * MODOUT;
        float acc = modb2[(size_t)c * MODOUT + o];
        const float* wp = modw2 + (size_t)c * HMODL * MODOUT + o;
        const float* hrow = s_h2[b];
        for (int hh = 0; hh < HMODL; hh++)
            acc = fmaf(hrow[hh], wp[(size_t)hh * MODOUT], acc);
        if (o < 64)
            out_ctx[((size_t)b * NCC + c) * 64 + o] =
                ctxp[((size_t)b * NCC + c) * 64 + o] + acc;
        else
            out_bg[((size_t)b * NCC + c) * 4 + (o - 64)] =
                bglp[((size_t)b * NCC + c) * 4 + (o - 64)] + acc;
    }
}

extern "C" void kernel_launch(void* const* d_in, const int* in_sizes, int n_in,
                              void* d_out, int out_size, void* d_ws, size_t ws_size,
                              hipStream_t stream) {
    const float* xp     = (const float*)d_in[0];
    const float* hp     = (const float*)d_in[1];
    const float* msgp   = (const float*)d_in[2];
    const float* Wp     = (const float*)d_in[3];
    const float* decayp = (const float*)d_in[4];
    const float* ctxp   = (const float*)d_in[5];
    const float* bglp   = (const float*)d_in[6];
    const float* nidp   = (const float*)d_in[7];
    const float* sw1    = (const float*)d_in[8];
    const float* sb1    = (const float*)d_in[9];
    const float* sgs1   = (const float*)d_in[10];
    const float* sgb1   = (const float*)d_in[11];
    const float* sw2    = (const float*)d_in[12];
    const float* sb2    = (const float*)d_in[13];
    const float* sgs2   = (const float*)d_in[14];
    const float* sgb2   = (const float*)d_in[15];
    const float* mw1    = (const float*)d_in[16];
    const float* mb1    = (const float*)d_in[17];
    const float* mgs1   = (const float*)d_in[18];
    const float* mgb1   = (const float*)d_in[19];
    const float* mw2    = (const float*)d_in[20];
    const float* mb2    = (const float*)d_in[21];
    const float* mgs2   = (const float*)d_in[22];
    const float* mgb2   = (const float*)d_in[23];
    const float* iw     = (const float*)d_in[24];
    const float* ibias  = (const float*)d_in[25];
    const float* modw1  = (const float*)d_in[26];
    const float* modb1  = (const float*)d_in[27];
    const float* modw2  = (const float*)d_in[28];
    const float* modb2  = (const float*)d_in[29];
    const int*   c2g    = (const int*)d_in[30];

    float* out      = (float*)d_out;
    float* out_read = out;                 // 524288
    float* out_h    = out_read + 524288;   // 33554432
    float* out_msg  = out_h + 33554432;    // 33554432
    float* out_ctx  = out_msg + 33554432;  // 524288
    float* out_bg   = out_ctx + 524288;    // 32768

    ushort_t* wb  = (ushort_t*)d_ws;                          // 160KB bf16 weights
    float*    wsf = (float*)((char*)d_ws + FEATS_BYTE_OFF);   // 8192 x 132 f32

    mg_cvtw<<<320, 256, 0, stream>>>(sw1, sw2, mw1, mw2, wb);

    mg_cell_kernel<<<8192, 512, 0, stream>>>(
        xp, hp, msgp, Wp, decayp, bglp, nidp,
        sb1, sgs1, sgb1, sb2, sgs2, sgb2,
        mb1, mgs1, mgb1, mb2, mgs2, mgb2,
        iw, ibias, c2g, wb, out_read, out_h, out_msg, wsf);

    mg_mod_kernel<<<1024, 256, 0, stream>>>(
        wsf, modw1, modb1, modw2, modb2, ctxp, bglp, out_ctx, out_bg);
}

// Round 4
// 829.227 us; speedup vs baseline: 1.1704x; 1.1704x over previous
//
#include <hip/hip_runtime.h>

#define NCC 1024
#define MODIN 198
#define MODOUT 68
#define HMODL 128

typedef __attribute__((ext_vector_type(8))) short s8v;   // 8 bf16 = 4 VGPR
typedef __attribute__((ext_vector_type(4))) float f4v;   // MFMA acc
typedef unsigned short ushort_t;
typedef unsigned int uint_t;

// ws layout (ushort elems): sw1 @0 (32768), sw2 @32768 (16384), mw1 @49152 (16384), mw2 @65536 (16384)
#define OFF_SW1 0
#define OFF_SW2 32768
#define OFF_MW1 49152
#define OFF_MW2 65536
#define FEATS_BYTE_OFF 262144   // feats: 8192 cells x 132 f32

__device__ __forceinline__ float fast_tanh(float x) {
    const float e = __builtin_amdgcn_exp2f(x * 2.885390081777927f);   // e^{2x}
    const float r = __builtin_amdgcn_rcpf(e + 1.f);
    return fmaf(-2.f, r, 1.f);
}
__device__ __forceinline__ float fast_sigmoid(float x) {
    const float e = __builtin_amdgcn_exp2f(x * -1.4426950408889634f);
    return __builtin_amdgcn_rcpf(e + 1.f);
}
__device__ __forceinline__ ushort_t f2bf(float x) {   // RNE f32->bf16
    uint_t u = __builtin_bit_cast(uint_t, x);
    u += 0x7FFFu + ((u >> 16) & 1u);
    return (ushort_t)(u >> 16);
}
__device__ __forceinline__ uint_t pk2(float a, float b) {
    return (uint_t)f2bf(a) | ((uint_t)f2bf(b) << 16);
}
// XOR swizzle on LDS byte offsets (16B granule): kills the power-of-2-stride bank conflict
#define SWZ(byteoff, row) ((byteoff) ^ (((row) & 7) << 4))

// ---------------------------------------------------------------------------
// Kernel 0: convert the 4 shared MLP weight matrices to bf16 once per launch
// ---------------------------------------------------------------------------
__global__ __launch_bounds__(256)
void mg_cvtw(const float* __restrict__ sw1, const float* __restrict__ sw2,
             const float* __restrict__ mw1, const float* __restrict__ mw2,
             ushort_t* __restrict__ o) {
    const int i = blockIdx.x * 256 + threadIdx.x;   // grid 320 -> 81920 exact
    float v;
    if (i < 32768)      v = sw1[i];
    else if (i < 49152) v = sw2[i - 32768];
    else if (i < 65536) v = mw1[i - 49152];
    else                v = mw2[i - 65536];
    o[i] = f2bf(v);
}

// ---------------------------------------------------------------------------
// Kernel 1: per (b, cell) block; 256 threads = 4 waves (round-2 structure,
// 6 barriers instead of 8, no LDS atomics, split MFMA K-chains).
// mfma_f32_16x16x32_bf16 layouts (m89-verified, round-2-proven):
//   A-frag: row = lane&15, k = (lane>>4)*8 + j
//   B-frag (from [N][K] row-major): col = lane&15, k contiguous
//   D: col = lane&15, row = (lane>>4)*4 + reg
// ---------------------------------------------------------------------------
__global__ __launch_bounds__(256, 3)
void mg_cell_kernel(
    const float* __restrict__ xp,   const float* __restrict__ hp,
    const float* __restrict__ msgp, const float* __restrict__ Wp,
    const float* __restrict__ decayp, const float* __restrict__ bglp,
    const float* __restrict__ nidp,
    const float* __restrict__ sb1,  const float* __restrict__ sgs1,
    const float* __restrict__ sgb1, const float* __restrict__ sb2,
    const float* __restrict__ sgs2, const float* __restrict__ sgb2,
    const float* __restrict__ mb1,  const float* __restrict__ mgs1,
    const float* __restrict__ mgb1, const float* __restrict__ mb2,
    const float* __restrict__ mgs2, const float* __restrict__ mgb2,
    const float* __restrict__ iw,   const float* __restrict__ ibias,
    const int*   __restrict__ c2g,  const ushort_t* __restrict__ wb,
    float* __restrict__ out_read, float* __restrict__ out_h,
    float* __restrict__ out_msg,  float* __restrict__ wsf)
{
    const int t  = threadIdx.x;
    const int bc = blockIdx.x;
    const int b  = bc >> 10, c = bc & 1023;
    const int gh = c >> 5, gwc = c & 31;
    const int lane = t & 63, w = t >> 6;
    const int cl = lane & 15, q = lane >> 4;
    const int g  = c2g[c];
    const size_t tile = (size_t)bc * 4096;

    __shared__ ushort_t sHid[16384];   // [64][256] bf16 32KB; first 16KB overlays sW|sMsgT
    __shared__ ushort_t sIn[8192];     // [64][128] bf16: [received/h_new | h]
    __shared__ float s_scr[256];       // border incoming; later [0:64]=hmean, [64:128]=mmean
    __shared__ float s_inj[256];
    __shared__ float s_dec[64];
    __shared__ float s_wsum[4];
    __shared__ float s_dsum;

    ushort_t* sW    = sHid;            // [64][64], row stride 128B
    ushort_t* sMsgT = sHid + 4096;     // [64 d][64 m]

    // ================= P0: staging + border + decay + inject =================
    {   // W -> sW bf16 (+ sum|W|): n = t>>2, 16 cols each (256 thr x 16 = 4096)
        const int n = t >> 2, m0 = (t & 3) * 16;
        const float* src = Wp + tile + n * 64 + m0;
        float wsum = 0.f;
        #pragma unroll
        for (int i = 0; i < 4; i++) {
            const float4 v = *(const float4*)(src + i * 4);
            wsum += fabsf(v.x) + fabsf(v.y) + fabsf(v.z) + fabsf(v.w);
            const int m = m0 + i * 4;
            *(uint_t*)((char*)sW + SWZ(n * 128 + m * 2, n))       = pk2(v.x, v.y);
            *(uint_t*)((char*)sW + SWZ(n * 128 + (m + 2) * 2, n)) = pk2(v.z, v.w);
        }
        #pragma unroll
        for (int off = 32; off > 0; off >>= 1) wsum += __shfl_down(wsum, off);
        if (lane == 0) s_wsum[w] = wsum;
    }
    #pragma unroll
    for (int i = 0; i < 4; i++) {   // msg^T -> sMsgT bf16
        const int m = (t >> 4) + i * 16, d0 = (t & 15) * 4;
        const float4 v = *(const float4*)(msgp + tile + (size_t)m * 64 + d0);
        *(ushort_t*)((char*)sMsgT + SWZ((d0 + 0) * 128 + m * 2, d0 + 0)) = f2bf(v.x);
        *(ushort_t*)((char*)sMsgT + SWZ((d0 + 1) * 128 + m * 2, d0 + 1)) = f2bf(v.y);
        *(ushort_t*)((char*)sMsgT + SWZ((d0 + 2) * 128 + m * 2, d0 + 2)) = f2bf(v.z);
        *(ushort_t*)((char*)sMsgT + SWZ((d0 + 3) * 128 + m * 2, d0 + 3)) = f2bf(v.w);
    }
    #pragma unroll
    for (int i = 0; i < 4; i++) {   // h -> sIn[:,64:128] bf16
        const int n = (t >> 4) + i * 16, d0 = (t & 15) * 4;
        const float4 v = *(const float4*)(hp + tile + (size_t)n * 64 + d0);
        *(uint_t*)((char*)sIn + SWZ(n * 256 + (64 + d0) * 2, n))     = pk2(v.x, v.y);
        *(uint_t*)((char*)sIn + SWZ(n * 256 + (64 + d0 + 2) * 2, n)) = pk2(v.z, v.w);
    }
    {   // gated border incoming: wave p = w
        const int p = w, dd = lane;
        int ok, nc2, qq;
        if      (p == 0) { ok = (gh > 0);   nc2 = c - 32; qq = 1; }
        else if (p == 1) { ok = (gh < 31);  nc2 = c + 32; qq = 0; }
        else if (p == 2) { ok = (gwc > 0);  nc2 = c - 1;  qq = 3; }
        else             { ok = (gwc < 31); nc2 = c + 1;  qq = 2; }
        float v = 0.f;
        if (ok) v = msgp[((size_t)b * NCC + nc2) * 4096 + (8 + qq) * 64 + dd];
        s_scr[p * 64 + dd] = fast_sigmoid(bglp[(size_t)bc * 4 + p]) * v;
    }
    if (w == 0) {   // decay sigmoid table + logit sum
        const float dl = decayp[(size_t)bc * 64 + lane];
        s_dec[lane] = fast_sigmoid(dl);
        float v = dl;
        #pragma unroll
        for (int off = 32; off > 0; off >>= 1) v += __shfl_down(v, off);
        if (lane == 0) s_dsum = v;
    }
    {   // inject: s_inj[t] = iw[g][t] . x  (x via wave-uniform loads -> SMEM)
        const float* xrow = xp + ((size_t)b * NCC + c) * 64;
        const float* wrow = iw + (size_t)g * 16384 + t * 64;
        float acc = ibias[g * 256 + t];
        #pragma unroll
        for (int i = 0; i < 64; i += 4) {
            const float4 w4 = *(const float4*)(wrow + i);
            const float4 x4 = *(const float4*)(xrow + i);
            acc = fmaf(w4.x, x4.x, acc); acc = fmaf(w4.y, x4.y, acc);
            acc = fmaf(w4.z, x4.z, acc); acc = fmaf(w4.w, x4.w, acc);
        }
        s_inj[t] = acc;
    }
    __syncthreads();   // B1

    const f4v fzero = {0.f, 0.f, 0.f, 0.f};
    const int d = 16 * w + cl;   // this thread's d-column in P1/P4/P6

    // ========== P1: W@msg (MFMA) fused with +inject +border -> sIn[:,0:64] ==========
    {
        f4v wm[4] = {fzero, fzero, fzero, fzero};
        __builtin_amdgcn_s_setprio(1);
        #pragma unroll
        for (int ks = 0; ks < 2; ks++) {
            const int k0 = ks * 32 + q * 8;
            const s8v bf = *(const s8v*)((const char*)sMsgT + SWZ(d * 128 + k0 * 2, d));
            #pragma unroll
            for (int rt = 0; rt < 4; rt++) {
                const int ar = rt * 16 + cl;
                const s8v af = *(const s8v*)((const char*)sW + SWZ(ar * 128 + k0 * 2, ar));
                wm[rt] = __builtin_amdgcn_mfma_f32_16x16x32_bf16(af, bf, wm[rt], 0, 0, 0);
            }
        }
        __builtin_amdgcn_s_setprio(0);
        #pragma unroll
        for (int rt = 0; rt < 4; rt++)
            #pragma unroll
            for (int r = 0; r < 4; r++) {
                const int n = rt * 16 + q * 4 + r;
                float v = wm[rt][r];
                if (n < 4)                 v += s_inj[n * 64 + d];
                else if (n >= 8 && n < 12) v += s_scr[(n - 8) * 64 + d];
                *(ushort_t*)((char*)sIn + SWZ(n * 256 + d * 2, n)) = f2bf(v);
            }
    }
    __syncthreads();   // B2

    // ================= P3: state L1 [64x128]@[128x256]^T -> sHid =================
    {
        f4v acc[4][4];
        #pragma unroll
        for (int i = 0; i < 4; i++)
            #pragma unroll
            for (int j = 0; j < 4; j++) acc[i][j] = fzero;
        const ushort_t* wb1 = wb + OFF_SW1;
        __builtin_amdgcn_s_setprio(1);
        #pragma unroll
        for (int ks = 0; ks < 4; ks++) {
            const int k0 = ks * 32 + q * 8;
            s8v bfr[4], afr[4];
            #pragma unroll
            for (int ct = 0; ct < 4; ct++)
                bfr[ct] = *(const s8v*)(wb1 + (64 * w + ct * 16 + cl) * 128 + k0);
            #pragma unroll
            for (int rt = 0; rt < 4; rt++) {
                const int ar = rt * 16 + cl;
                afr[rt] = *(const s8v*)((const char*)sIn + SWZ(ar * 256 + k0 * 2, ar));
            }
            #pragma unroll
            for (int rt = 0; rt < 4; rt++)
                #pragma unroll
                for (int ct = 0; ct < 4; ct++)
                    acc[rt][ct] = __builtin_amdgcn_mfma_f32_16x16x32_bf16(afr[rt], bfr[ct], acc[rt][ct], 0, 0, 0);
        }
        __builtin_amdgcn_s_setprio(0);
        #pragma unroll
        for (int ct = 0; ct < 4; ct++) {
            const int hcol = 64 * w + ct * 16 + cl;
            const float b1 = sb1[hcol], g1 = sgs1[g * 256 + hcol], o1 = sgb1[g * 256 + hcol];
            #pragma unroll
            for (int rt = 0; rt < 4; rt++)
                #pragma unroll
                for (int r = 0; r < 4; r++) {
                    const int n = rt * 16 + q * 4 + r;
                    const float vv = fast_tanh(fmaf(acc[rt][ct][r] + b1, g1, o1));
                    *(ushort_t*)((char*)sHid + SWZ(n * 512 + hcol * 2, n)) = f2bf(vv);
                }
        }
    }
    __syncthreads();   // B3

    // ===== P4: state L2 -> cand -> h_new (store global + sIn bf16) + h_mean =====
    {
        f4v a2[4][2];
        #pragma unroll
        for (int i = 0; i < 4; i++) { a2[i][0] = fzero; a2[i][1] = fzero; }
        const ushort_t* wb2 = wb + OFF_SW2;
        __builtin_amdgcn_s_setprio(1);
        #pragma unroll
        for (int ks = 0; ks < 8; ks++) {   // even/odd split halves the acc dep chain
            const int k0 = ks * 32 + q * 8;
            const s8v bf = *(const s8v*)(wb2 + d * 256 + k0);
            #pragma unroll
            for (int rt = 0; rt < 4; rt++) {
                const int ar = rt * 16 + cl;
                const s8v af = *(const s8v*)((const char*)sHid + SWZ(ar * 512 + k0 * 2, ar));
                a2[rt][ks & 1] = __builtin_amdgcn_mfma_f32_16x16x32_bf16(af, bf, a2[rt][ks & 1], 0, 0, 0);
            }
        }
        __builtin_amdgcn_s_setprio(0);
        const float b2 = sb2[d], g2 = sgs2[g * 64 + d], o2 = sgb2[g * 64 + d];
        float hsum = 0.f;
        #pragma unroll
        for (int rt = 0; rt < 4; rt++)
            #pragma unroll
            for (int r = 0; r < 4; r++) {
                const int n = rt * 16 + q * 4 + r;
                const float cand = fast_tanh(fmaf(a2[rt][0][r] + a2[rt][1][r] + b2, g2, o2));
                const ushort_t hu = *(const ushort_t*)((const char*)sIn + SWZ(n * 256 + (64 + d) * 2, n));
                const float hv = __builtin_bit_cast(float, (uint_t)hu << 16);
                const float hn = fmaf(s_dec[n], hv - cand, cand);   // dec*h + (1-dec)*cand
                out_h[tile + (size_t)n * 64 + d] = hn;
                *(ushort_t*)((char*)sIn + SWZ(n * 256 + d * 2, n)) = f2bf(hn);
                hsum += hn;
            }
        hsum += __shfl_xor(hsum, 16);
        hsum += __shfl_xor(hsum, 32);
        if (q == 0) s_scr[d] = hsum;   // hmean band [0:64); border region is dead
    }
    __syncthreads();   // B4

    // ================= P5: msg L1 [64x64]@[64x256]^T -> sHid =================
    {
        f4v acc[4][4];
        #pragma unroll
        for (int i = 0; i < 4; i++)
            #pragma unroll
            for (int j = 0; j < 4; j++) acc[i][j] = fzero;
        const ushort_t* wb1 = wb + OFF_MW1;
        __builtin_amdgcn_s_setprio(1);
        #pragma unroll
        for (int ks = 0; ks < 2; ks++) {
            const int k0 = ks * 32 + q * 8;
            s8v bfr[4], afr[4];
            #pragma unroll
            for (int ct = 0; ct < 4; ct++)
                bfr[ct] = *(const s8v*)(wb1 + (64 * w + ct * 16 + cl) * 64 + k0);
            #pragma unroll
            for (int rt = 0; rt < 4; rt++) {
                const int ar = rt * 16 + cl;
                afr[rt] = *(const s8v*)((const char*)sIn + SWZ(ar * 256 + k0 * 2, ar));
            }
            #pragma unroll
            for (int rt = 0; rt < 4; rt++)
                #pragma unroll
                for (int ct = 0; ct < 4; ct++)
                    acc[rt][ct] = __builtin_amdgcn_mfma_f32_16x16x32_bf16(afr[rt], bfr[ct], acc[rt][ct], 0, 0, 0);
        }
        __builtin_amdgcn_s_setprio(0);
        #pragma unroll
        for (int ct = 0; ct < 4; ct++) {
            const int hcol = 64 * w + ct * 16 + cl;
            const float b1 = mb1[hcol], g1 = mgs1[g * 256 + hcol], o1 = mgb1[g * 256 + hcol];
            #pragma unroll
            for (int rt = 0; rt < 4; rt++)
                #pragma unroll
                for (int r = 0; r < 4; r++) {
                    const int n = rt * 16 + q * 4 + r;
                    const float vv = fast_tanh(fmaf(acc[rt][ct][r] + b1, g1, o1));
                    *(ushort_t*)((char*)sHid + SWZ(n * 512 + hcol * 2, n)) = f2bf(vv);
                }
        }
    }
    __syncthreads();   // B5

    // ========== P6: msg L2 -> msg_new (+nid), msg_mean, readout ==========
    {
        f4v a2[4][2];
        #pragma unroll
        for (int i = 0; i < 4; i++) { a2[i][0] = fzero; a2[i][1] = fzero; }
        const ushort_t* wb2 = wb + OFF_MW2;
        __builtin_amdgcn_s_setprio(1);
        #pragma unroll
        for (int ks = 0; ks < 8; ks++) {
            const int k0 = ks * 32 + q * 8;
            const s8v bf = *(const s8v*)(wb2 + d * 256 + k0);
            #pragma unroll
            for (int rt = 0; rt < 4; rt++) {
                const int ar = rt * 16 + cl;
                const s8v af = *(const s8v*)((const char*)sHid + SWZ(ar * 512 + k0 * 2, ar));
                a2[rt][ks & 1] = __builtin_amdgcn_mfma_f32_16x16x32_bf16(af, bf, a2[rt][ks & 1], 0, 0, 0);
            }
        }
        __builtin_amdgcn_s_setprio(0);
        const float b2 = mb2[d], g2 = mgs2[g * 64 + d], o2 = mgb2[g * 64 + d];
        float msum = 0.f, ro = 0.f;
        #pragma unroll
        for (int rt = 0; rt < 4; rt++)
            #pragma unroll
            for (int r = 0; r < 4; r++) {
                const int n = rt * 16 + q * 4 + r;
                const float mv = fast_tanh(fmaf(a2[rt][0][r] + a2[rt][1][r] + b2, g2, o2))
                                 + nidp[(size_t)c * 4096 + (size_t)n * 64 + d];
                out_msg[tile + (size_t)n * 64 + d] = mv;
                msum += mv;
                if (rt == 0 && q == 1) ro += mv;   // output ports n = 4..7
            }
        msum += __shfl_xor(msum, 16);
        msum += __shfl_xor(msum, 32);
        if (q == 0) s_scr[64 + d] = msum;   // mmean band [64:128)
        if (q == 1) out_read[((size_t)b * NCC + c) * 64 + d] = ro * 0.5f;
    }
    __syncthreads();   // B6

    // ================= P7: feats record (130 values) =================
    if (t < 132) {
        float v = 0.f;
        if (t < 128)       v = s_scr[t] * (1.f / 64.f);
        else if (t == 128) v = (s_wsum[0] + s_wsum[1] + s_wsum[2] + s_wsum[3]) * (1.f / 4096.f);
        else if (t == 129) v = s_dsum * (1.f / 64.f);
        wsf[(size_t)bc * 132 + t] = v;
    }
}

// ---------------------------------------------------------------------------
// Kernel 2: per-cell modulation MLP (distinct weights per cell)
// ---------------------------------------------------------------------------
__global__ __launch_bounds__(256, 2)
void mg_mod_kernel(
    const float* __restrict__ wsf,   const float* __restrict__ modw1,
    const float* __restrict__ modb1, const float* __restrict__ modw2,
    const float* __restrict__ modb2, const float* __restrict__ ctxp,
    const float* __restrict__ bglp,  float* __restrict__ out_ctx,
    float* __restrict__ out_bg)
{
    const int c = blockIdx.x;
    const int t = threadIdx.x;
    __shared__ float s_f[8][MODIN];
    __shared__ float s_h2[8][HMODL];

    for (int k = t; k < 8 * MODIN; k += 256) {
        const int b = k / MODIN, f = k - b * MODIN;
        float v;
        if (f < 130)      v = wsf[((size_t)b * NCC + c) * 132 + f];
        else if (f < 194) v = ctxp[((size_t)b * NCC + c) * 64 + (f - 130)];
        else              v = bglp[((size_t)b * NCC + c) * 4 + (f - 194)];
        s_f[b][f] = v;
    }
    __syncthreads();

    {
        const int hh = t & 127, bh = (t >> 7) * 4;
        float a0 = 0.f, a1 = 0.f, a2 = 0.f, a3 = 0.f;
        const float* wp = modw1 + (size_t)c * MODIN * HMODL + hh;
        for (int f = 0; f < MODIN; f++) {
            const float wv = wp[(size_t)f * HMODL];
            a0 = fmaf(s_f[bh + 0][f], wv, a0);
            a1 = fmaf(s_f[bh + 1][f], wv, a1);
            a2 = fmaf(s_f[bh + 2][f], wv, a2);
            a3 = fmaf(s_f[bh + 3][f], wv, a3);
        }
        const float bv = modb1[(size_t)c * HMODL + hh];
        s_h2[bh + 0][hh] = fast_tanh(a0 + bv);
        s_h2[bh + 1][hh] = fast_tanh(a1 + bv);
        s_h2[bh + 2][hh] = fast_tanh(a2 + bv);
        s_h2[bh + 3][hh] = fast_tanh(a3 + bv);
    }
    __syncthreads();

    for (int idx = t; idx < 8 * MODOUT; idx += 256) {
        const int b = idx / MODOUT, o = idx - b * MODOUT;
        float acc = modb2[(size_t)c * MODOUT + o];
        const float* wp = modw2 + (size_t)c * HMODL * MODOUT + o;
        const float* hrow = s_h2[b];
        for (int hh = 0; hh < HMODL; hh++)
            acc = fmaf(hrow[hh], wp[(size_t)hh * MODOUT], acc);
        if (o < 64)
            out_ctx[((size_t)b * NCC + c) * 64 + o] =
                ctxp[((size_t)b * NCC + c) * 64 + o] + acc;
        else
            out_bg[((size_t)b * NCC + c) * 4 + (o - 64)] =
                bglp[((size_t)b * NCC + c) * 4 + (o - 64)] + acc;
    }
}

extern "C" void kernel_launch(void* const* d_in, const int* in_sizes, int n_in,
                              void* d_out, int out_size, void* d_ws, size_t ws_size,
                              hipStream_t stream) {
    const float* xp     = (const float*)d_in[0];
    const float* hp     = (const float*)d_in[1];
    const float* msgp   = (const float*)d_in[2];
    const float* Wp     = (const float*)d_in[3];
    const float* decayp = (const float*)d_in[4];
    const float* ctxp   = (const float*)d_in[5];
    const float* bglp   = (const float*)d_in[6];
    const float* nidp   = (const float*)d_in[7];
    const float* sw1    = (const float*)d_in[8];
    const float* sb1    = (const float*)d_in[9];
    const float* sgs1   = (const float*)d_in[10];
    const float* sgb1   = (const float*)d_in[11];
    const float* sw2    = (const float*)d_in[12];
    const float* sb2    = (const float*)d_in[13];
    const float* sgs2   = (const float*)d_in[14];
    const float* sgb2   = (const float*)d_in[15];
    const float* mw1    = (const float*)d_in[16];
    const float* mb1    = (const float*)d_in[17];
    const float* mgs1   = (const float*)d_in[18];
    const float* mgb1   = (const float*)d_in[19];
    const float* mw2    = (const float*)d_in[20];
    const float* mb2    = (const float*)d_in[21];
    const float* mgs2   = (const float*)d_in[22];
    const float* mgb2   = (const float*)d_in[23];
    const float* iw     = (const float*)d_in[24];
    const float* ibias  = (const float*)d_in[25];
    const float* modw1  = (const float*)d_in[26];
    const float* modb1  = (const float*)d_in[27];
    const float* modw2  = (const float*)d_in[28];
    const float* modb2  = (const float*)d_in[29];
    const int*   c2g    = (const int*)d_in[30];

    float* out      = (float*)d_out;
    float* out_read = out;                 // 524288
    float* out_h    = out_read + 524288;   // 33554432
    float* out_msg  = out_h + 33554432;    // 33554432
    float* out_ctx  = out_msg + 33554432;  // 524288
    float* out_bg   = out_ctx + 524288;    // 32768

    ushort_t* wb  = (ushort_t*)d_ws;                          // 160KB bf16 weights
    float*    wsf = (float*)((char*)d_ws + FEATS_BYTE_OFF);   // 8192 x 132 f32

    mg_cvtw<<<320, 256, 0, stream>>>(sw1, sw2, mw1, mw2, wb);

    mg_cell_kernel<<<8192, 256, 0, stream>>>(
        xp, hp, msgp, Wp, decayp, bglp, nidp,
        sb1, sgs1, sgb1, sb2, sgs2, sgb2,
        mb1, mgs1, mgb1, mb2, mgs2, mgb2,
        iw, ibias, c2g, wb, out_read, out_h, out_msg, wsf);

    mg_mod_kernel<<<1024, 256, 0, stream>>>(
        wsf, modw1, modb1, modw2, modb2, ctxp, bglp, out_ctx, out_bg);
}

// Round 5
// 571.805 us; speedup vs baseline: 1.6973x; 1.4502x over previous
//
#include <hip/hip_runtime.h>

#define NCC 1024
#define MODIN 198
#define MODOUT 68
#define HMODL 128

typedef __attribute__((ext_vector_type(8))) short s8v;   // 8 bf16 = 4 VGPR
typedef __attribute__((ext_vector_type(4))) float f4v;   // MFMA acc
typedef unsigned short ushort_t;
typedef unsigned int uint_t;

// ws layout (ushort elems): sw1 @0 (32768), sw2 @32768 (16384), mw1 @49152 (16384), mw2 @65536 (16384)
#define OFF_SW1 0
#define OFF_SW2 32768
#define OFF_MW1 49152
#define OFF_MW2 65536
#define FEATS_BYTE_OFF 262144   // feats: 8192 cells x 132 f32

__device__ __forceinline__ float fast_tanh(float x) {
    const float e = __builtin_amdgcn_exp2f(x * 2.885390081777927f);   // e^{2x}
    const float r = __builtin_amdgcn_rcpf(e + 1.f);
    return fmaf(-2.f, r, 1.f);
}
__device__ __forceinline__ float fast_sigmoid(float x) {
    const float e = __builtin_amdgcn_exp2f(x * -1.4426950408889634f);
    return __builtin_amdgcn_rcpf(e + 1.f);
}
__device__ __forceinline__ ushort_t f2bf(float x) {   // RNE f32->bf16
    uint_t u = __builtin_bit_cast(uint_t, x);
    u += 0x7FFFu + ((u >> 16) & 1u);
    return (ushort_t)(u >> 16);
}
__device__ __forceinline__ uint_t pk2(float a, float b) {
    return (uint_t)f2bf(a) | ((uint_t)f2bf(b) << 16);
}
// XOR swizzle on LDS byte offsets (16B granule)
#define SWZ(byteoff, row) ((byteoff) ^ (((row) & 7) << 4))

// ---------------------------------------------------------------------------
// Kernel 0: convert the 4 shared MLP weight matrices to bf16 once per launch
// ---------------------------------------------------------------------------
__global__ __launch_bounds__(256)
void mg_cvtw(const float* __restrict__ sw1, const float* __restrict__ sw2,
             const float* __restrict__ mw1, const float* __restrict__ mw2,
             ushort_t* __restrict__ o) {
    const int i = blockIdx.x * 256 + threadIdx.x;   // grid 320 -> 81920 exact
    float v;
    if (i < 32768)      v = sw1[i];
    else if (i < 49152) v = sw2[i - 32768];
    else if (i < 65536) v = mw1[i - 49152];
    else                v = mw2[i - 65536];
    o[i] = f2bf(v);
}

// ---------------------------------------------------------------------------
// Kernel 0b: inject[b,c,o] = x[b,c,:] . iw[g(c)][o,:] + ib[g(c)][o]
// One block per cell c; all 8 batches share the 64KB iw read (8x traffic cut).
// Output goes into the first 1KB of each out_h tile (P1 reads it, P4 overwrites).
// ---------------------------------------------------------------------------
__global__ __launch_bounds__(256, 4)
void mg_inject(const float* __restrict__ xp, const float* __restrict__ iw,
               const float* __restrict__ ibias, const int* __restrict__ c2g,
               float* __restrict__ injb) {
    const int c = blockIdx.x, t = threadIdx.x;
    const int g = c2g[c];
    __shared__ float s_x[8][64];
    for (int idx = t; idx < 512; idx += 256)
        s_x[idx >> 6][idx & 63] = xp[(size_t)(idx >> 6) * (NCC * 64) + c * 64 + (idx & 63)];
    __syncthreads();
    const float* wrow = iw + (size_t)g * 16384 + t * 64;
    float a0 = 0.f, a1 = 0.f, a2 = 0.f, a3 = 0.f, a4 = 0.f, a5 = 0.f, a6 = 0.f, a7 = 0.f;
    #pragma unroll
    for (int i = 0; i < 64; i += 4) {
        const float4 w4 = *(const float4*)(wrow + i);
        const float4 x0 = *(const float4*)&s_x[0][i];
        const float4 x1 = *(const float4*)&s_x[1][i];
        const float4 x2 = *(const float4*)&s_x[2][i];
        const float4 x3 = *(const float4*)&s_x[3][i];
        const float4 x4 = *(const float4*)&s_x[4][i];
        const float4 x5 = *(const float4*)&s_x[5][i];
        const float4 x6 = *(const float4*)&s_x[6][i];
        const float4 x7 = *(const float4*)&s_x[7][i];
        a0 = fmaf(w4.x, x0.x, a0); a0 = fmaf(w4.y, x0.y, a0); a0 = fmaf(w4.z, x0.z, a0); a0 = fmaf(w4.w, x0.w, a0);
        a1 = fmaf(w4.x, x1.x, a1); a1 = fmaf(w4.y, x1.y, a1); a1 = fmaf(w4.z, x1.z, a1); a1 = fmaf(w4.w, x1.w, a1);
        a2 = fmaf(w4.x, x2.x, a2); a2 = fmaf(w4.y, x2.y, a2); a2 = fmaf(w4.z, x2.z, a2); a2 = fmaf(w4.w, x2.w, a2);
        a3 = fmaf(w4.x, x3.x, a3); a3 = fmaf(w4.y, x3.y, a3); a3 = fmaf(w4.z, x3.z, a3); a3 = fmaf(w4.w, x3.w, a3);
        a4 = fmaf(w4.x, x4.x, a4); a4 = fmaf(w4.y, x4.y, a4); a4 = fmaf(w4.z, x4.z, a4); a4 = fmaf(w4.w, x4.w, a4);
        a5 = fmaf(w4.x, x5.x, a5); a5 = fmaf(w4.y, x5.y, a5); a5 = fmaf(w4.z, x5.z, a5); a5 = fmaf(w4.w, x5.w, a5);
        a6 = fmaf(w4.x, x6.x, a6); a6 = fmaf(w4.y, x6.y, a6); a6 = fmaf(w4.z, x6.z, a6); a6 = fmaf(w4.w, x6.w, a6);
        a7 = fmaf(w4.x, x7.x, a7); a7 = fmaf(w4.y, x7.y, a7); a7 = fmaf(w4.z, x7.z, a7); a7 = fmaf(w4.w, x7.w, a7);
    }
    const float bv = ibias[g * 256 + t];
    const float acc[8] = {a0, a1, a2, a3, a4, a5, a6, a7};
    #pragma unroll
    for (int b = 0; b < 8; b++)
        injb[((size_t)b * NCC + c) * 4096 + t] = acc[b] + bv;   // out_h tile head
}

// ---------------------------------------------------------------------------
// Kernel 1: per (b, cell) block; 256 threads = 4 waves; 6 barriers.
// Two-pass ct in P3/P5 keeps live VGPRs ~56 in the fat phases (anti-spill).
// mfma_f32_16x16x32_bf16 layouts (proven rounds 2-4):
//   A-frag: row = lane&15, k = (lane>>4)*8 + j
//   B-frag (from [N][K] row-major): col = lane&15, k contiguous
//   D: col = lane&15, row = (lane>>4)*4 + reg
// ---------------------------------------------------------------------------
__global__ __launch_bounds__(256, 3)
void mg_cell_kernel(
    const float* __restrict__ hp,   const float* __restrict__ msgp,
    const float* __restrict__ Wp,   const float* __restrict__ decayp,
    const float* __restrict__ bglp, const float* __restrict__ nidp,
    const float* __restrict__ sb1,  const float* __restrict__ sgs1,
    const float* __restrict__ sgb1, const float* __restrict__ sb2,
    const float* __restrict__ sgs2, const float* __restrict__ sgb2,
    const float* __restrict__ mb1,  const float* __restrict__ mgs1,
    const float* __restrict__ mgb1, const float* __restrict__ mb2,
    const float* __restrict__ mgs2, const float* __restrict__ mgb2,
    const int*   __restrict__ c2g,  const ushort_t* __restrict__ wb,
    float* __restrict__ out_read, float* __restrict__ out_h,
    float* __restrict__ out_msg,  float* __restrict__ wsf)
{
    const int t  = threadIdx.x;
    const int bc = blockIdx.x;
    const int b  = bc >> 10, c = bc & 1023;
    const int gh = c >> 5, gwc = c & 31;
    const int lane = t & 63, w = t >> 6;
    const int cl = lane & 15, q = lane >> 4;
    const int g  = c2g[c];
    const size_t tile = (size_t)bc * 4096;

    __shared__ ushort_t sHid[16384];   // [64][256] bf16 32KB; first 16KB overlays sW|sMsgT
    __shared__ ushort_t sIn[8192];     // [64][128] bf16: [received/h_new | h]
    __shared__ float s_scr[256];       // border incoming; later [0:64]=hmean, [64:128]=mmean
    __shared__ float s_dec[64];
    __shared__ float s_wsum[4];
    __shared__ float s_dsum;

    ushort_t* sW    = sHid;            // [64][64], row stride 128B
    ushort_t* sMsgT = sHid + 4096;     // [64 d][64 m]

    // ================= P0: staging + border + decay =================
    {   // W -> sW bf16 (+ sum|W|)
        const int n = t >> 2, m0 = (t & 3) * 16;
        const float* src = Wp + tile + n * 64 + m0;
        float wsum = 0.f;
        #pragma unroll
        for (int i = 0; i < 4; i++) {
            const float4 v = *(const float4*)(src + i * 4);
            wsum += fabsf(v.x) + fabsf(v.y) + fabsf(v.z) + fabsf(v.w);
            const int m = m0 + i * 4;
            *(uint_t*)((char*)sW + SWZ(n * 128 + m * 2, n))       = pk2(v.x, v.y);
            *(uint_t*)((char*)sW + SWZ(n * 128 + (m + 2) * 2, n)) = pk2(v.z, v.w);
        }
        #pragma unroll
        for (int off = 32; off > 0; off >>= 1) wsum += __shfl_down(wsum, off);
        if (lane == 0) s_wsum[w] = wsum;
    }
    #pragma unroll
    for (int i = 0; i < 4; i++) {   // msg^T -> sMsgT bf16
        const int m = (t >> 4) + i * 16, d0 = (t & 15) * 4;
        const float4 v = *(const float4*)(msgp + tile + (size_t)m * 64 + d0);
        *(ushort_t*)((char*)sMsgT + SWZ((d0 + 0) * 128 + m * 2, d0 + 0)) = f2bf(v.x);
        *(ushort_t*)((char*)sMsgT + SWZ((d0 + 1) * 128 + m * 2, d0 + 1)) = f2bf(v.y);
        *(ushort_t*)((char*)sMsgT + SWZ((d0 + 2) * 128 + m * 2, d0 + 2)) = f2bf(v.z);
        *(ushort_t*)((char*)sMsgT + SWZ((d0 + 3) * 128 + m * 2, d0 + 3)) = f2bf(v.w);
    }
    #pragma unroll
    for (int i = 0; i < 4; i++) {   // h -> sIn[:,64:128] bf16
        const int n = (t >> 4) + i * 16, d0 = (t & 15) * 4;
        const float4 v = *(const float4*)(hp + tile + (size_t)n * 64 + d0);
        *(uint_t*)((char*)sIn + SWZ(n * 256 + (64 + d0) * 2, n))     = pk2(v.x, v.y);
        *(uint_t*)((char*)sIn + SWZ(n * 256 + (64 + d0 + 2) * 2, n)) = pk2(v.z, v.w);
    }
    {   // gated border incoming: wave p = w
        const int p = w, dd = lane;
        int ok, nc2, qq;
        if      (p == 0) { ok = (gh > 0);   nc2 = c - 32; qq = 1; }
        else if (p == 1) { ok = (gh < 31);  nc2 = c + 32; qq = 0; }
        else if (p == 2) { ok = (gwc > 0);  nc2 = c - 1;  qq = 3; }
        else             { ok = (gwc < 31); nc2 = c + 1;  qq = 2; }
        float v = 0.f;
        if (ok) v = msgp[((size_t)b * NCC + nc2) * 4096 + (8 + qq) * 64 + dd];
        s_scr[p * 64 + dd] = fast_sigmoid(bglp[(size_t)bc * 4 + p]) * v;
    }
    if (w == 0) {   // decay sigmoid table + logit sum
        const float dl = decayp[(size_t)bc * 64 + lane];
        s_dec[lane] = fast_sigmoid(dl);
        float v = dl;
        #pragma unroll
        for (int off = 32; off > 0; off >>= 1) v += __shfl_down(v, off);
        if (lane == 0) s_dsum = v;
    }
    __syncthreads();   // B1

    const f4v fzero = {0.f, 0.f, 0.f, 0.f};
    const int d = 16 * w + cl;   // this thread's d-column in P1/P4/P6

    // ========== P1: W@msg (MFMA) + inject(precomputed) + border -> sIn[:,0:64] ==========
    {
        f4v wm[4] = {fzero, fzero, fzero, fzero};
        // prefetch inject for this thread's n<4 rows (lives in out_h tile head)
        float injv[4] = {0.f, 0.f, 0.f, 0.f};
        if (q == 0) {
            #pragma unroll
            for (int r = 0; r < 4; r++) injv[r] = out_h[tile + r * 64 + d];
        }
        __builtin_amdgcn_s_setprio(1);
        #pragma unroll
        for (int ks = 0; ks < 2; ks++) {
            const int k0 = ks * 32 + q * 8;
            const s8v bf = *(const s8v*)((const char*)sMsgT + SWZ(d * 128 + k0 * 2, d));
            #pragma unroll
            for (int rt = 0; rt < 4; rt++) {
                const int ar = rt * 16 + cl;
                const s8v af = *(const s8v*)((const char*)sW + SWZ(ar * 128 + k0 * 2, ar));
                wm[rt] = __builtin_amdgcn_mfma_f32_16x16x32_bf16(af, bf, wm[rt], 0, 0, 0);
            }
        }
        __builtin_amdgcn_s_setprio(0);
        #pragma unroll
        for (int rt = 0; rt < 4; rt++)
            #pragma unroll
            for (int r = 0; r < 4; r++) {
                const int n = rt * 16 + q * 4 + r;
                float v = wm[rt][r];
                if (n < 4)                 v += injv[r];
                else if (n >= 8 && n < 12) v += s_scr[(n - 8) * 64 + d];
                *(ushort_t*)((char*)sIn + SWZ(n * 256 + d * 2, n)) = f2bf(v);
            }
    }
    __syncthreads();   // B2

    // ===== P3: state L1 [64x128]@[128x256]^T -> sHid (two ct-passes, low VGPR) =====
    {
        const ushort_t* wb1 = wb + OFF_SW1;
        #pragma unroll
        for (int cp = 0; cp < 2; cp++) {
            f4v acc[4][2];
            #pragma unroll
            for (int i = 0; i < 4; i++) { acc[i][0] = fzero; acc[i][1] = fzero; }
            __builtin_amdgcn_s_setprio(1);
            #pragma unroll
            for (int ks = 0; ks < 4; ks++) {
                const int k0 = ks * 32 + q * 8;
                const s8v bf0 = *(const s8v*)(wb1 + (64 * w + (cp * 2 + 0) * 16 + cl) * 128 + k0);
                const s8v bf1 = *(const s8v*)(wb1 + (64 * w + (cp * 2 + 1) * 16 + cl) * 128 + k0);
                #pragma unroll
                for (int rt = 0; rt < 4; rt++) {
                    const int ar = rt * 16 + cl;
                    const s8v af = *(const s8v*)((const char*)sIn + SWZ(ar * 256 + k0 * 2, ar));
                    acc[rt][0] = __builtin_amdgcn_mfma_f32_16x16x32_bf16(af, bf0, acc[rt][0], 0, 0, 0);
                    acc[rt][1] = __builtin_amdgcn_mfma_f32_16x16x32_bf16(af, bf1, acc[rt][1], 0, 0, 0);
                }
            }
            __builtin_amdgcn_s_setprio(0);
            #pragma unroll
            for (int ct2 = 0; ct2 < 2; ct2++) {
                const int hcol = 64 * w + (cp * 2 + ct2) * 16 + cl;
                const float b1 = sb1[hcol], g1 = sgs1[g * 256 + hcol], o1 = sgb1[g * 256 + hcol];
                #pragma unroll
                for (int rt = 0; rt < 4; rt++)
                    #pragma unroll
                    for (int r = 0; r < 4; r++) {
                        const int n = rt * 16 + q * 4 + r;
                        const float vv = fast_tanh(fmaf(acc[rt][ct2][r] + b1, g1, o1));
                        *(ushort_t*)((char*)sHid + SWZ(n * 512 + hcol * 2, n)) = f2bf(vv);
                    }
            }
        }
    }
    __syncthreads();   // B3

    // ===== P4: state L2 -> cand -> h_new (store global + sIn bf16) + h_mean =====
    {
        f4v a2[4][2];
        #pragma unroll
        for (int i = 0; i < 4; i++) { a2[i][0] = fzero; a2[i][1] = fzero; }
        const ushort_t* wb2 = wb + OFF_SW2;
        __builtin_amdgcn_s_setprio(1);
        #pragma unroll
        for (int ks = 0; ks < 8; ks++) {
            const int k0 = ks * 32 + q * 8;
            const s8v bf = *(const s8v*)(wb2 + d * 256 + k0);
            #pragma unroll
            for (int rt = 0; rt < 4; rt++) {
                const int ar = rt * 16 + cl;
                const s8v af = *(const s8v*)((const char*)sHid + SWZ(ar * 512 + k0 * 2, ar));
                a2[rt][ks & 1] = __builtin_amdgcn_mfma_f32_16x16x32_bf16(af, bf, a2[rt][ks & 1], 0, 0, 0);
            }
        }
        __builtin_amdgcn_s_setprio(0);
        const float b2 = sb2[d], g2 = sgs2[g * 64 + d], o2 = sgb2[g * 64 + d];
        float hsum = 0.f;
        #pragma unroll
        for (int rt = 0; rt < 4; rt++)
            #pragma unroll
            for (int r = 0; r < 4; r++) {
                const int n = rt * 16 + q * 4 + r;
                const float cand = fast_tanh(fmaf(a2[rt][0][r] + a2[rt][1][r] + b2, g2, o2));
                const ushort_t hu = *(const ushort_t*)((const char*)sIn + SWZ(n * 256 + (64 + d) * 2, n));
                const float hv = __builtin_bit_cast(float, (uint_t)hu << 16);
                const float hn = fmaf(s_dec[n], hv - cand, cand);   // dec*h + (1-dec)*cand
                out_h[tile + (size_t)n * 64 + d] = hn;
                *(ushort_t*)((char*)sIn + SWZ(n * 256 + d * 2, n)) = f2bf(hn);
                hsum += hn;
            }
        hsum += __shfl_xor(hsum, 16);
        hsum += __shfl_xor(hsum, 32);
        if (q == 0) s_scr[d] = hsum;   // hmean band [0:64)
    }
    __syncthreads();   // B4

    // ===== P5: msg L1 [64x64]@[64x256]^T -> sHid (two ct-passes) =====
    {
        const ushort_t* wb1 = wb + OFF_MW1;
        #pragma unroll
        for (int cp = 0; cp < 2; cp++) {
            f4v acc[4][2];
            #pragma unroll
            for (int i = 0; i < 4; i++) { acc[i][0] = fzero; acc[i][1] = fzero; }
            __builtin_amdgcn_s_setprio(1);
            #pragma unroll
            for (int ks = 0; ks < 2; ks++) {
                const int k0 = ks * 32 + q * 8;
                const s8v bf0 = *(const s8v*)(wb1 + (64 * w + (cp * 2 + 0) * 16 + cl) * 64 + k0);
                const s8v bf1 = *(const s8v*)(wb1 + (64 * w + (cp * 2 + 1) * 16 + cl) * 64 + k0);
                #pragma unroll
                for (int rt = 0; rt < 4; rt++) {
                    const int ar = rt * 16 + cl;
                    const s8v af = *(const s8v*)((const char*)sIn + SWZ(ar * 256 + k0 * 2, ar));
                    acc[rt][0] = __builtin_amdgcn_mfma_f32_16x16x32_bf16(af, bf0, acc[rt][0], 0, 0, 0);
                    acc[rt][1] = __builtin_amdgcn_mfma_f32_16x16x32_bf16(af, bf1, acc[rt][1], 0, 0, 0);
                }
            }
            __builtin_amdgcn_s_setprio(0);
            #pragma unroll
            for (int ct2 = 0; ct2 < 2; ct2++) {
                const int hcol = 64 * w + (cp * 2 + ct2) * 16 + cl;
                const float b1 = mb1[hcol], g1 = mgs1[g * 256 + hcol], o1 = mgb1[g * 256 + hcol];
                #pragma unroll
                for (int rt = 0; rt < 4; rt++)
                    #pragma unroll
                    for (int r = 0; r < 4; r++) {
                        const int n = rt * 16 + q * 4 + r;
                        const float vv = fast_tanh(fmaf(acc[rt][ct2][r] + b1, g1, o1));
                        *(ushort_t*)((char*)sHid + SWZ(n * 512 + hcol * 2, n)) = f2bf(vv);
                    }
            }
        }
    }
    __syncthreads();   // B5

    // ========== P6: msg L2 -> msg_new (+nid), msg_mean, readout ==========
    {
        // prefetch neuron_id (latency hidden under the MFMA cluster)
        float nv[16];
        #pragma unroll
        for (int rt = 0; rt < 4; rt++)
            #pragma unroll
            for (int r = 0; r < 4; r++) {
                const int n = rt * 16 + q * 4 + r;
                nv[rt * 4 + r] = nidp[(size_t)c * 4096 + (size_t)n * 64 + d];
            }
        f4v a2[4][2];
        #pragma unroll
        for (int i = 0; i < 4; i++) { a2[i][0] = fzero; a2[i][1] = fzero; }
        const ushort_t* wb2 = wb + OFF_MW2;
        __builtin_amdgcn_s_setprio(1);
        #pragma unroll
        for (int ks = 0; ks < 8; ks++) {
            const int k0 = ks * 32 + q * 8;
            const s8v bf = *(const s8v*)(wb2 + d * 256 + k0);
            #pragma unroll
            for (int rt = 0; rt < 4; rt++) {
                const int ar = rt * 16 + cl;
                const s8v af = *(const s8v*)((const char*)sHid + SWZ(ar * 512 + k0 * 2, ar));
                a2[rt][ks & 1] = __builtin_amdgcn_mfma_f32_16x16x32_bf16(af, bf, a2[rt][ks & 1], 0, 0, 0);
            }
        }
        __builtin_amdgcn_s_setprio(0);
        const float b2 = mb2[d], g2 = mgs2[g * 64 + d], o2 = mgb2[g * 64 + d];
        float msum = 0.f, ro = 0.f;
        #pragma unroll
        for (int rt = 0; rt < 4; rt++)
            #pragma unroll
            for (int r = 0; r < 4; r++) {
                const int n = rt * 16 + q * 4 + r;
                const float mv = fast_tanh(fmaf(a2[rt][0][r] + a2[rt][1][r] + b2, g2, o2))
                                 + nv[rt * 4 + r];
                out_msg[tile + (size_t)n * 64 + d] = mv;
                msum += mv;
                if (rt == 0 && q == 1) ro += mv;   // output ports n = 4..7
            }
        msum += __shfl_xor(msum, 16);
        msum += __shfl_xor(msum, 32);
        if (q == 0) s_scr[64 + d] = msum;   // mmean band [64:128)
        if (q == 1) out_read[((size_t)b * NCC + c) * 64 + d] = ro * 0.5f;
    }
    __syncthreads();   // B6

    // ================= P7: feats record (130 values) =================
    if (t < 132) {
        float v = 0.f;
        if (t < 128)       v = s_scr[t] * (1.f / 64.f);
        else if (t == 128) v = (s_wsum[0] + s_wsum[1] + s_wsum[2] + s_wsum[3]) * (1.f / 4096.f);
        else if (t == 129) v = s_dsum * (1.f / 64.f);
        wsf[(size_t)bc * 132 + t] = v;
    }
}

// ---------------------------------------------------------------------------
// Kernel 2: per-cell modulation MLP (distinct weights per cell)
// ---------------------------------------------------------------------------
__global__ __launch_bounds__(256, 2)
void mg_mod_kernel(
    const float* __restrict__ wsf,   const float* __restrict__ modw1,
    const float* __restrict__ modb1, const float* __restrict__ modw2,
    const float* __restrict__ modb2, const float* __restrict__ ctxp,
    const float* __restrict__ bglp,  float* __restrict__ out_ctx,
    float* __restrict__ out_bg)
{
    const int c = blockIdx.x;
    const int t = threadIdx.x;
    __shared__ float s_f[8][MODIN];
    __shared__ float s_h2[8][HMODL];

    for (int k = t; k < 8 * MODIN; k += 256) {
        const int b = k / MODIN, f = k - b * MODIN;
        float v;
        if (f < 130)      v = wsf[((size_t)b * NCC + c) * 132 + f];
        else if (f < 194) v = ctxp[((size_t)b * NCC + c) * 64 + (f - 130)];
        else              v = bglp[((size_t)b * NCC + c) * 4 + (f - 194)];
        s_f[b][f] = v;
    }
    __syncthreads();

    {
        const int hh = t & 127, bh = (t >> 7) * 4;
        float a0 = 0.f, a1 = 0.f, a2 = 0.f, a3 = 0.f;
        const float* wp = modw1 + (size_t)c * MODIN * HMODL + hh;
        for (int f = 0; f < MODIN; f++) {
            const float wv = wp[(size_t)f * HMODL];
            a0 = fmaf(s_f[bh + 0][f], wv, a0);
            a1 = fmaf(s_f[bh + 1][f], wv, a1);
            a2 = fmaf(s_f[bh + 2][f], wv, a2);
            a3 = fmaf(s_f[bh + 3][f], wv, a3);
        }
        const float bv = modb1[(size_t)c * HMODL + hh];
        s_h2[bh + 0][hh] = fast_tanh(a0 + bv);
        s_h2[bh + 1][hh] = fast_tanh(a1 + bv);
        s_h2[bh + 2][hh] = fast_tanh(a2 + bv);
        s_h2[bh + 3][hh] = fast_tanh(a3 + bv);
    }
    __syncthreads();

    for (int idx = t; idx < 8 * MODOUT; idx += 256) {
        const int b = idx / MODOUT, o = idx - b * MODOUT;
        float acc = modb2[(size_t)c * MODOUT + o];
        const float* wp = modw2 + (size_t)c * HMODL * MODOUT + o;
        const float* hrow = s_h2[b];
        for (int hh = 0; hh < HMODL; hh++)
            acc = fmaf(hrow[hh], wp[(size_t)hh * MODOUT], acc);
        if (o < 64)
            out_ctx[((size_t)b * NCC + c) * 64 + o] =
                ctxp[((size_t)b * NCC + c) * 64 + o] + acc;
        else
            out_bg[((size_t)b * NCC + c) * 4 + (o - 64)] =
                bglp[((size_t)b * NCC + c) * 4 + (o - 64)] + acc;
    }
}

extern "C" void kernel_launch(void* const* d_in, const int* in_sizes, int n_in,
                              void* d_out, int out_size, void* d_ws, size_t ws_size,
                              hipStream_t stream) {
    const float* xp     = (const float*)d_in[0];
    const float* hp     = (const float*)d_in[1];
    const float* msgp   = (const float*)d_in[2];
    const float* Wp     = (const float*)d_in[3];
    const float* decayp = (const float*)d_in[4];
    const float* ctxp   = (const float*)d_in[5];
    const float* bglp   = (const float*)d_in[6];
    const float* nidp   = (const float*)d_in[7];
    const float* sw1    = (const float*)d_in[8];
    const float* sb1    = (const float*)d_in[9];
    const float* sgs1   = (const float*)d_in[10];
    const float* sgb1   = (const float*)d_in[11];
    const float* sw2    = (const float*)d_in[12];
    const float* sb2    = (const float*)d_in[13];
    const float* sgs2   = (const float*)d_in[14];
    const float* sgb2   = (const float*)d_in[15];
    const float* mw1    = (const float*)d_in[16];
    const float* mb1    = (const float*)d_in[17];
    const float* mgs1   = (const float*)d_in[18];
    const float* mgb1   = (const float*)d_in[19];
    const float* mw2    = (const float*)d_in[20];
    const float* mb2    = (const float*)d_in[21];
    const float* mgs2   = (const float*)d_in[22];
    const float* mgb2   = (const float*)d_in[23];
    const float* iw     = (const float*)d_in[24];
    const float* ibias  = (const float*)d_in[25];
    const float* modw1  = (const float*)d_in[26];
    const float* modb1  = (const float*)d_in[27];
    const float* modw2  = (const float*)d_in[28];
    const float* modb2  = (const float*)d_in[29];
    const int*   c2g    = (const int*)d_in[30];

    float* out      = (float*)d_out;
    float* out_read = out;                 // 524288
    float* out_h    = out_read + 524288;   // 33554432
    float* out_msg  = out_h + 33554432;    // 33554432
    float* out_ctx  = out_msg + 33554432;  // 524288
    float* out_bg   = out_ctx + 524288;    // 32768

    ushort_t* wb  = (ushort_t*)d_ws;                          // 160KB bf16 weights
    float*    wsf = (float*)((char*)d_ws + FEATS_BYTE_OFF);   // 8192 x 132 f32

    mg_cvtw<<<320, 256, 0, stream>>>(sw1, sw2, mw1, mw2, wb);

    // inject -> head of each out_h tile (read by P1, overwritten by P4)
    mg_inject<<<1024, 256, 0, stream>>>(xp, iw, ibias, c2g, out_h);

    mg_cell_kernel<<<8192, 256, 0, stream>>>(
        hp, msgp, Wp, decayp, bglp, nidp,
        sb1, sgs1, sgb1, sb2, sgs2, sgb2,
        mb1, mgs1, mgb1, mb2, mgs2, mgb2,
        c2g, wb, out_read, out_h, out_msg, wsf);

    mg_mod_kernel<<<1024, 256, 0, stream>>>(
        wsf, modw1, modb1, modw2, modb2, ctxp, bglp, out_ctx, out_bg);
}